// Round 5
// baseline (1135.734 us; speedup 1.0000x reference)
//
#include <hip/hip_runtime.h>
#include <math.h>

#define BD 512      // input dim D
#define HH 128      // hidden dim H
#define KSEL 358    // output dim K (top-k)
#define TR 8        // rows per block
#define NT 256      // threads per block

__device__ __forceinline__ int wave_sum64(int v) {
    #pragma unroll
    for (int off = 32; off > 0; off >>= 1) v += __shfl_xor(v, off, 64);
    return v;
}

// XLA:CPU / Eigen pexp-float (classic cephes) bit-emulation.
// Quadrant via floor(fma(x, log2e, 0.5)); Cody-Waite two-step reduction with
// NON-contracted mul/sub (Eigen uses pmul+psub here); degree-5 Horner in FMA
// (Eigen pmadd); final fma(p, r^2, r) + 1; exact 2^m scaling via exponent add.
__device__ __forceinline__ float cephes_expf(float x) {
    x = fminf(x, 88.3762626647950f);
    x = fmaxf(x, -88.3762626647949f);
    float m = floorf(fmaf(x, 1.44269504088896341f, 0.5f));
    float r = __fsub_rn(x, __fmul_rn(m, 0.693359375f));
    r = __fsub_rn(r, __fmul_rn(m, -2.12194440e-4f));
    float r2 = __fmul_rn(r, r);
    float p = 1.9875691500E-4f;
    p = fmaf(p, r, 1.3981999507E-3f);
    p = fmaf(p, r, 8.3334519073E-3f);
    p = fmaf(p, r, 4.1665795894E-2f);
    p = fmaf(p, r, 1.6666665459E-1f);
    p = fmaf(p, r, 5.0000001201E-1f);
    float y = __fadd_rn(fmaf(p, r2, r), 1.0f);
    int mi = (int)m;
    y = __int_as_float(__float_as_int(y) + (mi << 23));   // y in [~0.7,1.5]: safe
    return y;
}

// XLA logistic expansion: 1 / (1 + exp(-z)), IEEE fp32 add and divide.
__device__ __forceinline__ float sig_xla(float z) {
    float t = cephes_expf(-z);
    float d = __fadd_rn(1.0f, t);
    return __fdiv_rn(1.0f, d);
}

__global__ __launch_bounds__(NT, 2)
void afs_fused(const float* __restrict__ x,
               const float* __restrict__ W1,  const float* __restrict__ b1,
               const float* __restrict__ W2,  const float* __restrict__ b2,
               const float* __restrict__ W3,  const float* __restrict__ b3,
               const float* __restrict__ Wg1, const float* __restrict__ bg1,
               const float* __restrict__ Wg2, const float* __restrict__ bg2,
               const float* __restrict__ Wr1, const float* __restrict__ br1,
               const float* __restrict__ Wr2, const float* __restrict__ br2,
               float* __restrict__ out)
{
    __shared__ float xs[TR][BD];    // 16 KB; masked in place
    __shared__ float h1s[TR][HH];   // 4 KB
    __shared__ float g1s[TR][HH];   // 4 KB
    __shared__ float h2s[TR][HH];   // 4 KB
    __shared__ float cs[TR][BD];    // 16 KB combined scores (fp32 = ref arithmetic)
    __shared__ float rs[TR][HH];    // 4 KB

    const int tid = threadIdx.x;
    const long long row0 = (long long)blockIdx.x * TR;

    // ---------- Phase 0: load x tile ----------
    {
        const float4* src = reinterpret_cast<const float4*>(x + row0 * BD);
        float4* dst = reinterpret_cast<float4*>(&xs[0][0]);
        #pragma unroll
        for (int i = 0; i < (TR * BD / 4) / NT; ++i)
            dst[tid + i * NT] = src[tid + i * NT];
    }
    __syncthreads();

    // ---------- Phase 1: h1 = relu(x@W1+b1), g1 = relu(x@Wg1+bg1) ----------
    // Eigen/XLA semantics: single k-block, sequential-k, one accumulator,
    // bias added afterwards as a separate fp32 add.
    {
        const int c = tid & (HH - 1);
        const int rbase = (tid >> 7) * 4;
        float a1[4] = {0.f, 0.f, 0.f, 0.f};
        float ga[4] = {0.f, 0.f, 0.f, 0.f};
        for (int k = 0; k < BD; ++k) {
            float w1 = W1[k * HH + c];
            float wg = Wg1[k * HH + c];
            #pragma unroll
            for (int r = 0; r < 4; ++r) {
                float xv = xs[rbase + r][k];
                a1[r] = fmaf(xv, w1, a1[r]);
                ga[r] = fmaf(xv, wg, ga[r]);
            }
        }
        float bb1 = b1[c], bbg = bg1[c];
        #pragma unroll
        for (int r = 0; r < 4; ++r) {
            float v1 = __fadd_rn(a1[r], bb1);
            float vg = __fadd_rn(ga[r], bbg);
            h1s[rbase + r][c] = v1 > 0.f ? v1 : 0.f;
            g1s[rbase + r][c] = vg > 0.f ? vg : 0.f;
        }
    }
    __syncthreads();

    // ---------- Phase 2: h2 = relu(h1@W2+b2)  [k=128 sequential] ----------
    {
        const int c = tid & (HH - 1);
        const int rbase = (tid >> 7) * 4;
        float acc[4] = {0.f, 0.f, 0.f, 0.f};
        for (int k = 0; k < HH; ++k) {
            float w = W2[k * HH + c];
            #pragma unroll
            for (int r = 0; r < 4; ++r)
                acc[r] = fmaf(h1s[rbase + r][k], w, acc[r]);
        }
        float bb = b2[c];
        #pragma unroll
        for (int r = 0; r < 4; ++r) {
            float v = __fadd_rn(acc[r], bb);
            h2s[rbase + r][c] = v > 0.f ? v : 0.f;
        }
    }
    __syncthreads();

    // ---------- Phase 3: cs = sig(h2@W3+b3) * sig(g1@Wg2+bg2) ----------
    {
        const int c0 = tid, c1 = tid + NT;
        float z0[TR], z1[TR];
        #pragma unroll
        for (int r = 0; r < TR; ++r) { z0[r] = 0.f; z1[r] = 0.f; }
        for (int k = 0; k < HH; ++k) {
            float w0 = W3[k * BD + c0];
            float w1 = W3[k * BD + c1];
            #pragma unroll
            for (int r = 0; r < TR; ++r) {
                float hv = h2s[r][k];
                z0[r] = fmaf(hv, w0, z0[r]);
                z1[r] = fmaf(hv, w1, z1[r]);
            }
        }
        {
            float bi0 = b3[c0], bi1 = b3[c1];
            #pragma unroll
            for (int r = 0; r < TR; ++r) {
                cs[r][c0] = sig_xla(__fadd_rn(z0[r], bi0));
                cs[r][c1] = sig_xla(__fadd_rn(z1[r], bi1));
            }
        }
        #pragma unroll
        for (int r = 0; r < TR; ++r) { z0[r] = 0.f; z1[r] = 0.f; }
        for (int k = 0; k < HH; ++k) {
            float w0 = Wg2[k * BD + c0];
            float w1 = Wg2[k * BD + c1];
            #pragma unroll
            for (int r = 0; r < TR; ++r) {
                float gv = g1s[r][k];
                z0[r] = fmaf(gv, w0, z0[r]);
                z1[r] = fmaf(gv, w1, z1[r]);
            }
        }
        {
            float bq0 = bg2[c0], bq1 = bg2[c1];
            #pragma unroll
            for (int r = 0; r < TR; ++r) {
                cs[r][c0] = __fmul_rn(cs[r][c0], sig_xla(__fadd_rn(z0[r], bq0)));
                cs[r][c1] = __fmul_rn(cs[r][c1], sig_xla(__fadd_rn(z1[r], bq1)));
            }
        }
    }
    __syncthreads();

    // ---------- Phase 4: per-row top-K, exact on fp32 keys ----------
    // Positive fp32 -> value order == u32 bit order. Exact K-th largest via
    // binary search; bit-equal ties lowest-index-first (lax.top_k).
    {
        const int lane = tid & 63;
        const int wv = tid >> 6;
        for (int rr = 0; rr < 2; ++rr) {
            const int r = wv + rr * 4;
            unsigned u[8];
            #pragma unroll
            for (int j = 0; j < 8; ++j)
                u[j] = __float_as_uint(cs[r][j * 64 + lane]);

            unsigned lo = 0u, hi = 0xffffffffu;
            while (lo < hi) {
                unsigned mid = lo + ((hi - lo) >> 1);
                int cnt = 0;
                #pragma unroll
                for (int j = 0; j < 8; ++j) cnt += (u[j] > mid) ? 1 : 0;
                cnt = wave_sum64(cnt);
                if (cnt < KSEL) hi = mid; else lo = mid + 1;
            }
            const unsigned T = lo;

            int ngt = 0, neq = 0;
            #pragma unroll
            for (int j = 0; j < 8; ++j) {
                ngt += (u[j] > T) ? 1 : 0;
                neq += (u[j] == T) ? 1 : 0;
            }
            ngt = wave_sum64(ngt);
            neq = wave_sum64(neq);
            const int m = KSEL - ngt;

            unsigned selbits = 0;
            #pragma unroll
            for (int j = 0; j < 8; ++j)
                if (u[j] > T) selbits |= (1u << j);

            if (neq == m) {
                #pragma unroll
                for (int j = 0; j < 8; ++j)
                    if (u[j] == T) selbits |= (1u << j);
            } else {
                int cnt8[8];
                #pragma unroll
                for (int j = 0; j < 8; ++j) cnt8[j] = 0;
                for (int jj = 0; jj < BD; ++jj) {
                    unsigned uj = __float_as_uint(cs[r][jj]);
                    if (uj == T) {
                        #pragma unroll
                        for (int j = 0; j < 8; ++j)
                            cnt8[j] += (u[j] == T && jj < (j * 64 + lane)) ? 1 : 0;
                    }
                }
                #pragma unroll
                for (int j = 0; j < 8; ++j)
                    if (u[j] == T && (ngt + cnt8[j]) < KSEL)
                        selbits |= (1u << j);
            }

            #pragma unroll
            for (int j = 0; j < 8; ++j)
                if (!(selbits & (1u << j))) xs[r][j * 64 + lane] = 0.0f;
        }
    }
    __syncthreads();

    // ---------- Phase R1: r = relu(masked@Wr1 + br1) ----------
    {
        const int c = tid & (HH - 1);
        const int rbase = (tid >> 7) * 4;
        float acc[4] = {0.f, 0.f, 0.f, 0.f};
        for (int k = 0; k < BD; ++k) {
            float w = Wr1[k * HH + c];
            #pragma unroll
            for (int r = 0; r < 4; ++r)
                acc[r] = fmaf(xs[rbase + r][k], w, acc[r]);
        }
        float bb = br1[c];
        #pragma unroll
        for (int r = 0; r < 4; ++r) {
            float v = acc[r] + bb;
            rs[rbase + r][c] = v > 0.f ? v : 0.f;
        }
    }
    __syncthreads();

    // ---------- Phase R2: out = r@Wr2 + br2 ----------
    {
        for (int cc = tid; cc < KSEL; cc += NT) {
            float acc[TR];
            #pragma unroll
            for (int r = 0; r < TR; ++r) acc[r] = 0.f;
            for (int k = 0; k < HH; ++k) {
                float w = Wr2[k * KSEL + cc];
                #pragma unroll
                for (int r = 0; r < TR; ++r)
                    acc[r] = fmaf(rs[r][k], w, acc[r]);
            }
            float bb = br2[cc];
            #pragma unroll
            for (int r = 0; r < TR; ++r)
                out[(row0 + r) * KSEL + cc] = acc[r] + bb;
        }
    }
}

extern "C" void kernel_launch(void* const* d_in, const int* in_sizes, int n_in,
                              void* d_out, int out_size, void* d_ws, size_t ws_size,
                              hipStream_t stream) {
    const float* x   = (const float*)d_in[0];
    const float* W1  = (const float*)d_in[1];
    const float* b1  = (const float*)d_in[2];
    const float* W2  = (const float*)d_in[3];
    const float* b2  = (const float*)d_in[4];
    const float* W3  = (const float*)d_in[5];
    const float* b3  = (const float*)d_in[6];
    const float* Wg1 = (const float*)d_in[7];
    const float* bg1 = (const float*)d_in[8];
    const float* Wg2 = (const float*)d_in[9];
    const float* bg2 = (const float*)d_in[10];
    const float* Wr1 = (const float*)d_in[11];
    const float* br1 = (const float*)d_in[12];
    const float* Wr2 = (const float*)d_in[13];
    const float* br2 = (const float*)d_in[14];
    float* out = (float*)d_out;

    const int nrows = in_sizes[0] / BD;          // 65536
    dim3 grid(nrows / TR), block(NT);
    afs_fused<<<grid, block, 0, stream>>>(x, W1, b1, W2, b2, W3, b3,
                                          Wg1, bg1, Wg2, bg2, Wr1, br1, Wr2, br2, out);
}